// Round 1
// baseline (718.496 us; speedup 1.0000x reference)
//
#include <hip/hip_runtime.h>
#include <math.h>

#define B_   2
#define H_   16
#define NSEQ 1024
#define DM   1024
#define DKV  64
#define QT   8
#define LNEPS 1e-5f

// ---------------- mask dtype detection ----------------
// attention_mask is jnp.bool_. Harness may upload as int32 (doc: "integer -> const int*")
// or as raw 1-byte bools. Random 0/1 data: if packed bytes, a 4-byte word is >1 with
// prob 7/8 per word -> scanning 256 words decides with certainty.
__global__ void detect_mask(const unsigned* __restrict__ mask_words, int* __restrict__ flag) {
    unsigned f = 0;
    for (int i = 0; i < 256; ++i) f |= (mask_words[i] > 1u) ? 1u : 0u;
    *flag = (int)f;   // 1 => packed uint8 bools, 0 => int32 0/1
}

// ---------------- generic tiled f32 GEMM ----------------
// out = A(2048xDM) @ W(DMxDM) + bias ;  perhead=1: scatter to [B][H][N][64]
// perhead=0: out row-major + resid added.
__global__ __launch_bounds__(256) void gemm64(
    const float* __restrict__ A, const float* __restrict__ W,
    const float* __restrict__ bias, const float* __restrict__ resid,
    float* __restrict__ out, int perhead)
{
    const int m0 = blockIdx.y * 64;
    const int c0 = blockIdx.x * 64;
    const int t  = threadIdx.x;
    const int tx = t & 15, ty = t >> 4;

    __shared__ float As[64][33];
    __shared__ float Bs[32][64];

    float acc[4][4] = {};

    const int rA = t >> 2, ckA = (t & 3) * 8;   // A tile 64x32
    const int kB = t >> 3, ccB = (t & 7) * 8;   // B tile 32x64

    for (int k0 = 0; k0 < DM; k0 += 32) {
        const float* pa = A + (size_t)(m0 + rA) * DM + k0 + ckA;
        float4 a0 = *(const float4*)pa;
        float4 a1 = *(const float4*)(pa + 4);
        const float* pb = W + (size_t)(k0 + kB) * DM + c0 + ccB;
        float4 b0 = *(const float4*)pb;
        float4 b1 = *(const float4*)(pb + 4);
        As[rA][ckA+0]=a0.x; As[rA][ckA+1]=a0.y; As[rA][ckA+2]=a0.z; As[rA][ckA+3]=a0.w;
        As[rA][ckA+4]=a1.x; As[rA][ckA+5]=a1.y; As[rA][ckA+6]=a1.z; As[rA][ckA+7]=a1.w;
        *(float4*)&Bs[kB][ccB]   = b0;
        *(float4*)&Bs[kB][ccB+4] = b1;
        __syncthreads();
        #pragma unroll
        for (int kk = 0; kk < 32; ++kk) {
            float av[4], bv[4];
            #pragma unroll
            for (int i = 0; i < 4; ++i) av[i] = As[ty*4+i][kk];
            #pragma unroll
            for (int j = 0; j < 4; ++j) bv[j] = Bs[kk][tx*4+j];
            #pragma unroll
            for (int i = 0; i < 4; ++i)
                #pragma unroll
                for (int j = 0; j < 4; ++j)
                    acc[i][j] = fmaf(av[i], bv[j], acc[i][j]);
        }
        __syncthreads();
    }

    #pragma unroll
    for (int i = 0; i < 4; ++i) {
        const int m = m0 + ty*4 + i;
        #pragma unroll
        for (int j = 0; j < 4; ++j) {
            const int c = c0 + tx*4 + j;
            float v = acc[i][j] + bias[c];
            if (perhead) {
                const int b = m >> 10, n = m & (NSEQ - 1);
                const int h = c >> 6,  d = c & (DKV - 1);
                out[(((size_t)(b*H_ + h) * NSEQ) + n) * DKV + d] = v;
            } else {
                out[(size_t)m * DM + c] = v + resid[(size_t)m * DM + c];
            }
        }
    }
}

// ---------------- attention ----------------
// One block: (b,h) and QT=8 query rows. Two-pass: scores->LDS, softmax, PV.
__global__ __launch_bounds__(256) void attn_kernel(
    const float* __restrict__ Q, const float* __restrict__ K, const float* __restrict__ V,
    const void* __restrict__ mask, const float* __restrict__ wgt,
    const int* __restrict__ flagp, float* __restrict__ O)
{
    const int qt = blockIdx.x;           // 0..127
    const int h  = blockIdx.y, b = blockIdx.z;
    const int t  = threadIdx.x, lane = t & 63;
    const int q0 = qt * QT;

    __shared__ float Ss[QT][NSEQ];       // 32 KB
    __shared__ float KVs[64][65];        // 16.25 KB
    __shared__ float Qs[QT][64];         // 2 KB
    __shared__ float rowsum[QT];

    const size_t bh = (size_t)b * H_ + h;
    const float* Qp = Q + (bh * NSEQ + q0) * DKV;
    const float* Kp = K + bh * NSEQ * DKV;
    const float* Vp = V + bh * NSEQ * DKV;
    const float* Wp = wgt + (bh * NSEQ + q0) * NSEQ;
    const size_t moff = (bh * NSEQ + q0) * NSEQ;
    const int mmode = *flagp;
    const int* Mi = (const int*)mask;
    const unsigned char* Mb = (const unsigned char*)mask;

    {   // load Q tile 8x64
        int r = t >> 5, c = (t & 31) * 2;
        *(float2*)&Qs[r][c] = *(const float2*)(Qp + (size_t)r * DKV + c);
    }

    const int k = lane;
    const int rbase = t >> 6;            // 0..3 ; this thread owns rows rbase, rbase+4

    // ---- pass 1: scores ----
    for (int kc = 0; kc < NSEQ; kc += 64) {
        {   // stage K chunk 64x64
            int kk = t >> 2, c = (t & 3) * 16;
            #pragma unroll
            for (int u = 0; u < 4; ++u)
                *(float4*)&KVs[kk][c + u*4] = *(const float4*)(Kp + (size_t)(kc+kk)*DKV + c + u*4);
        }
        __syncthreads();
        float acc2[2] = {0.f, 0.f};
        #pragma unroll 8
        for (int d = 0; d < 64; ++d) {
            float kv = KVs[k][d];
            acc2[0] = fmaf(Qs[rbase][d],   kv, acc2[0]);
            acc2[1] = fmaf(Qs[rbase+4][d], kv, acc2[1]);
        }
        #pragma unroll
        for (int i = 0; i < 2; ++i) {
            int r = rbase + i*4;
            float w = Wp[(size_t)r*NSEQ + kc + k];
            bool m = mmode ? (Mb[moff + (size_t)r*NSEQ + kc + k] != 0)
                           : (Mi[moff + (size_t)r*NSEQ + kc + k] != 0);
            Ss[r][kc + k] = m ? -1e30f : acc2[i] * 0.125f * w;
        }
        __syncthreads();
    }

    // ---- softmax (wave w handles rows w, w+4) ----
    {
        int w = t >> 6;
        #pragma unroll
        for (int i = 0; i < 2; ++i) {
            int r = w + i*4;
            float mx = -1e30f;
            for (int kk2 = lane; kk2 < NSEQ; kk2 += 64) mx = fmaxf(mx, Ss[r][kk2]);
            #pragma unroll
            for (int off = 32; off > 0; off >>= 1) mx = fmaxf(mx, __shfl_xor(mx, off));
            float sum = 0.f;
            for (int kk2 = lane; kk2 < NSEQ; kk2 += 64) {
                float p = __expf(Ss[r][kk2] - mx);
                Ss[r][kk2] = p;
                sum += p;
            }
            #pragma unroll
            for (int off = 32; off > 0; off >>= 1) sum += __shfl_xor(sum, off);
            if (lane == 0) rowsum[r] = sum;
        }
    }
    __syncthreads();

    // ---- pass 2: PV ----
    float accO[2] = {0.f, 0.f};
    const int d = lane;
    for (int kc = 0; kc < NSEQ; kc += 64) {
        {   // stage V chunk 64x64
            int kk = t >> 2, c = (t & 3) * 16;
            #pragma unroll
            for (int u = 0; u < 4; ++u)
                *(float4*)&KVs[kk][c + u*4] = *(const float4*)(Vp + (size_t)(kc+kk)*DKV + c + u*4);
        }
        __syncthreads();
        #pragma unroll 8
        for (int kk = 0; kk < 64; ++kk) {
            float v = KVs[kk][d];
            accO[0] = fmaf(Ss[rbase][kc+kk],   v, accO[0]);
            accO[1] = fmaf(Ss[rbase+4][kc+kk], v, accO[1]);
        }
        __syncthreads();
    }
    #pragma unroll
    for (int i = 0; i < 2; ++i) {
        int r = rbase + i*4;
        O[((size_t)b*NSEQ + q0 + r)*DM + h*DKV + d] = accO[i] / rowsum[r];
    }
}

// ---------------- residual + LayerNorm ----------------
__global__ __launch_bounds__(256) void ln_kernel(
    const float* __restrict__ Y, const float* __restrict__ gamma,
    const float* __restrict__ beta, float* __restrict__ out)
{
    const int row = blockIdx.x;
    const int t = threadIdx.x;
    const float* y = Y + (size_t)row * DM;
    float4 x = *(const float4*)(y + t*4);
    __shared__ float red[4];
    float s = x.x + x.y + x.z + x.w;
    #pragma unroll
    for (int off = 32; off > 0; off >>= 1) s += __shfl_xor(s, off);
    if ((t & 63) == 0) red[t >> 6] = s;
    __syncthreads();
    float mean = (red[0]+red[1]+red[2]+red[3]) * (1.0f/DM);
    float d0 = x.x-mean, d1 = x.y-mean, d2 = x.z-mean, d3 = x.w-mean;
    float sq = d0*d0 + d1*d1 + d2*d2 + d3*d3;
    __syncthreads();
    #pragma unroll
    for (int off = 32; off > 0; off >>= 1) sq += __shfl_xor(sq, off);
    if ((t & 63) == 0) red[t >> 6] = sq;
    __syncthreads();
    float var = (red[0]+red[1]+red[2]+red[3]) * (1.0f/DM);
    float rstd = rsqrtf(var + LNEPS);
    int c = t * 4;
    float4 g  = *(const float4*)(gamma + c);
    float4 bb = *(const float4*)(beta + c);
    float4 o;
    o.x = d0*rstd*g.x + bb.x;
    o.y = d1*rstd*g.y + bb.y;
    o.z = d2*rstd*g.z + bb.z;
    o.w = d3*rstd*g.w + bb.w;
    *(float4*)(out + (size_t)row*DM + c) = o;
}

extern "C" void kernel_launch(void* const* d_in, const int* in_sizes, int n_in,
                              void* d_out, int out_size, void* d_ws, size_t ws_size,
                              hipStream_t stream)
{
    const float* queries = (const float*)d_in[0];
    const float* keys    = (const float*)d_in[1];
    const float* values  = (const float*)d_in[2];
    const void*  mask    = d_in[3];
    const float* wgt     = (const float*)d_in[4];
    const float* Wq = (const float*)d_in[5];  const float* bq = (const float*)d_in[6];
    const float* Wk = (const float*)d_in[7];  const float* bk = (const float*)d_in[8];
    const float* Wv = (const float*)d_in[9];  const float* bv = (const float*)d_in[10];
    const float* Wo = (const float*)d_in[11]; const float* bo = (const float*)d_in[12];
    const float* gamma = (const float*)d_in[13]; const float* beta = (const float*)d_in[14];
    float* out = (float*)d_out;

    char* ws = (char*)d_ws;
    int* flag = (int*)ws;
    const size_t SZ = (size_t)B_ * H_ * NSEQ * DKV;   // 2M floats per tensor
    float* Qb = (float*)(ws + 256);
    float* Kb = Qb + SZ;
    float* Vb = Kb + SZ;
    float* Ob = Vb + SZ;    // attention output, [B][N][H*DKV] row-major
    float* Yb = Ob + SZ;    // pre-LN (resid + proj)

    detect_mask<<<1, 1, 0, stream>>>((const unsigned*)mask, flag);
    gemm64<<<dim3(16, 32), 256, 0, stream>>>(queries, Wq, bq, nullptr, Qb, 1);
    gemm64<<<dim3(16, 32), 256, 0, stream>>>(keys,    Wk, bk, nullptr, Kb, 1);
    gemm64<<<dim3(16, 32), 256, 0, stream>>>(values,  Wv, bv, nullptr, Vb, 1);
    attn_kernel<<<dim3(NSEQ/QT, H_, B_), 256, 0, stream>>>(Qb, Kb, Vb, mask, wgt, flag, Ob);
    gemm64<<<dim3(16, 32), 256, 0, stream>>>(Ob, Wo, bo, queries, Yb, 0);
    ln_kernel<<<dim3(B_*NSEQ), 256, 0, stream>>>(Yb, gamma, beta, out);
}

// Round 3
// 384.464 us; speedup vs baseline: 1.8688x; 1.8688x over previous
//
#include <hip/hip_runtime.h>
#include <hip/hip_bf16.h>
#include <math.h>

#define B_   2
#define H_   16
#define NSEQ 1024
#define DM   1024
#define DKV  64
#define LNEPS 1e-5f

typedef __attribute__((ext_vector_type(8))) short s16x8;
typedef __attribute__((ext_vector_type(4))) float f32x4;

__device__ inline short f2bf(float f) {
    __hip_bfloat16 h = __float2bfloat16(f);
    return *reinterpret_cast<short*>(&h);
}

// ---------------- mask dtype detection ----------------
__global__ void detect_mask(const unsigned* __restrict__ mask_words, int* __restrict__ flag) {
    unsigned f = 0;
    for (int i = 0; i < 256; ++i) f |= (mask_words[i] > 1u) ? 1u : 0u;
    *flag = (int)f;   // 1 => packed uint8 bools, 0 => int32 0/1
}

// ---------------- tiled f32 GEMM, multi-mode epilogue ----------------
// A(2048xDM) @ W(DMxDM) + bias
// mode 0: f32 out row-major + resid
// mode 1: bf16 per-head [B][H][N][64]
// mode 2: bf16 per-head transposed [B][H][64][N]
__global__ __launch_bounds__(256) void gemm64(
    const float* __restrict__ A, const float* __restrict__ W,
    const float* __restrict__ bias, const float* __restrict__ resid,
    void* __restrict__ outp, int mode)
{
    const int m0 = blockIdx.y * 64;
    const int c0 = blockIdx.x * 64;
    const int t  = threadIdx.x;
    const int tx = t & 15, ty = t >> 4;

    __shared__ float As[64][33];
    __shared__ float Bs[32][64];

    float acc[4][4] = {};

    const int rA = t >> 2, ckA = (t & 3) * 8;   // A tile 64x32
    const int kB = t >> 3, ccB = (t & 7) * 8;   // B tile 32x64

    for (int k0 = 0; k0 < DM; k0 += 32) {
        const float* pa = A + (size_t)(m0 + rA) * DM + k0 + ckA;
        float4 a0 = *(const float4*)pa;
        float4 a1 = *(const float4*)(pa + 4);
        const float* pb = W + (size_t)(k0 + kB) * DM + c0 + ccB;
        float4 b0 = *(const float4*)pb;
        float4 b1 = *(const float4*)(pb + 4);
        As[rA][ckA+0]=a0.x; As[rA][ckA+1]=a0.y; As[rA][ckA+2]=a0.z; As[rA][ckA+3]=a0.w;
        As[rA][ckA+4]=a1.x; As[rA][ckA+5]=a1.y; As[rA][ckA+6]=a1.z; As[rA][ckA+7]=a1.w;
        *(float4*)&Bs[kB][ccB]   = b0;
        *(float4*)&Bs[kB][ccB+4] = b1;
        __syncthreads();
        #pragma unroll
        for (int kk = 0; kk < 32; ++kk) {
            float av[4], bv[4];
            #pragma unroll
            for (int i = 0; i < 4; ++i) av[i] = As[ty*4+i][kk];
            #pragma unroll
            for (int j = 0; j < 4; ++j) bv[j] = Bs[kk][tx*4+j];
            #pragma unroll
            for (int i = 0; i < 4; ++i)
                #pragma unroll
                for (int j = 0; j < 4; ++j)
                    acc[i][j] = fmaf(av[i], bv[j], acc[i][j]);
        }
        __syncthreads();
    }

    const int hh = c0 >> 6;  // head (modes 1/2); c0 is a multiple of 64
    #pragma unroll
    for (int i = 0; i < 4; ++i) {
        const int m = m0 + ty*4 + i;
        const int bb = m >> 10, n = m & (NSEQ - 1);
        float v[4];
        #pragma unroll
        for (int j = 0; j < 4; ++j) v[j] = acc[i][j] + bias[c0 + tx*4 + j];
        if (mode == 1) {
            short* ob = (short*)outp;
            uint u0 = (unsigned short)f2bf(v[0]) | ((unsigned)(unsigned short)f2bf(v[1]) << 16);
            uint u1 = (unsigned short)f2bf(v[2]) | ((unsigned)(unsigned short)f2bf(v[3]) << 16);
            uint2 pk; pk.x = u0; pk.y = u1;
            *(uint2*)(ob + (((size_t)(bb*H_ + hh) * NSEQ) + n) * DKV + tx*4) = pk;
        } else if (mode == 2) {
            short* ob = (short*)outp;
            #pragma unroll
            for (int j = 0; j < 4; ++j) {
                const int d = tx*4 + j;
                ob[(((size_t)(bb*H_ + hh) * DKV) + d) * NSEQ + n] = f2bf(v[j]);
            }
        } else {
            float* of = (float*)outp;
            #pragma unroll
            for (int j = 0; j < 4; ++j) {
                const int c = c0 + tx*4 + j;
                of[(size_t)m * DM + c] = v[j] + resid[(size_t)m * DM + c];
            }
        }
    }
}

// ---------------- flash attention, bf16 MFMA ----------------
// Swapped QK^T (S^T = K·Q^T). Two lane layouts per wave:
//   softmax layout: q-row = li  (C columns are lane-local scores)
//   C/O layout:     q-row = lg*4 + r  (MFMA C rows)
// All softmax state (m_run, l_run, factor) lives in softmax layout; anything
// applied to oacc must be shuffled from lane lg*4+r. (Round-2 bug: rescale
// used the lane's own factor.)
__global__ __launch_bounds__(256) void attn_mfma(
    const short* __restrict__ Qb, const short* __restrict__ Kb, const short* __restrict__ Vt,
    const void* __restrict__ mask, const float* __restrict__ wgt,
    const int* __restrict__ flagp, float* __restrict__ O)
{
    const int t  = threadIdx.x;
    const int wv = t >> 6;
    const int l  = t & 63;
    const int lg = l >> 4;     // 0..3
    const int li = l & 15;     // 0..15
    const int qt = blockIdx.x; // 16 tiles of 64 q-rows
    const int h  = blockIdx.y, b = blockIdx.z;
    const size_t bh = (size_t)b * H_ + h;
    const int qrow = qt*64 + wv*16 + li;            // this lane's softmax row

    __shared__ short Plds[4][16][80];               // per-wave P tile (bf16), 160B rows (16B-aligned)

    const short* Qp = Qb + (bh * NSEQ + qt*64 + wv*16) * DKV;
    const short* Kp = Kb + bh * NSEQ * DKV;
    const short* Vp = Vt + bh * DKV * NSEQ;
    const float* wrow = wgt + (bh * NSEQ + qrow) * NSEQ;
    const size_t moff = (bh * NSEQ + qrow) * NSEQ;
    const int mmode = *flagp;
    const unsigned* Mi = (const unsigned*)mask;
    const unsigned char* Mb = (const unsigned char*)mask;

    // Q fragments (held all kernel): row = li, d = dc*32 + lg*8 + e
    s16x8 qa[2];
    qa[0] = *(const s16x8*)(Qp + (size_t)li * DKV + lg*8);
    qa[1] = *(const s16x8*)(Qp + (size_t)li * DKV + 32 + lg*8);

    float m_run = -1e30f, l_run = 0.f;
    f32x4 oacc[4] = {};

    for (int kc = 0; kc < NSEQ; kc += 64) {
        // ---- S^T = K · Q^T : sc[nt][r] = S[q=li][key=kc+nt*16+lg*4+r] ----
        f32x4 sc[4] = {};
        #pragma unroll
        for (int dc = 0; dc < 2; ++dc) {
            #pragma unroll
            for (int nt = 0; nt < 4; ++nt) {
                s16x8 kb = *(const s16x8*)(Kp + (size_t)(kc + nt*16 + li) * DKV + dc*32 + lg*8);
                sc[nt] = __builtin_amdgcn_mfma_f32_16x16x32_bf16(kb, qa[dc], sc[nt], 0, 0, 0);
            }
        }

        // ---- scale * weights, mask, online softmax (softmax layout) ----
        float sv[16];
        float cmax = -1e30f;
        #pragma unroll
        for (int nt = 0; nt < 4; ++nt) {
            const int k4 = kc + nt*16 + lg*4;
            float4 w4 = *(const float4*)(wrow + k4);
            unsigned mm[4];
            if (mmode) {
                unsigned mb4 = *(const unsigned*)(Mb + moff + k4);
                mm[0] = mb4 & 0xffu; mm[1] = (mb4 >> 8) & 0xffu;
                mm[2] = (mb4 >> 16) & 0xffu; mm[3] = (mb4 >> 24) & 0xffu;
            } else {
                uint4 mi4 = *(const uint4*)(Mi + moff + k4);
                mm[0] = mi4.x; mm[1] = mi4.y; mm[2] = mi4.z; mm[3] = mi4.w;
            }
            float wv4[4] = {w4.x, w4.y, w4.z, w4.w};
            #pragma unroll
            for (int r = 0; r < 4; ++r) {
                float s = sc[nt][r] * 0.125f * wv4[r];
                s = mm[r] ? -1e30f : s;
                sv[nt*4 + r] = s;
                cmax = fmaxf(cmax, s);
            }
        }
        cmax = fmaxf(cmax, __shfl_xor(cmax, 16));
        cmax = fmaxf(cmax, __shfl_xor(cmax, 32));
        const float mnew = fmaxf(m_run, cmax);
        const float factor = __expf(m_run - mnew);
        m_run = mnew;

        float csum = 0.f;
        #pragma unroll
        for (int nt = 0; nt < 4; ++nt) {
            float p[4];
            #pragma unroll
            for (int r = 0; r < 4; ++r) {
                p[r] = __expf(sv[nt*4 + r] - mnew);
                csum += p[r];
            }
            uint u0 = (unsigned short)f2bf(p[0]) | ((unsigned)(unsigned short)f2bf(p[1]) << 16);
            uint u1 = (unsigned short)f2bf(p[2]) | ((unsigned)(unsigned short)f2bf(p[3]) << 16);
            uint2 pk; pk.x = u0; pk.y = u1;
            *(uint2*)&Plds[wv][li][nt*16 + lg*4] = pk;
        }
        csum += __shfl_xor(csum, 16);
        csum += __shfl_xor(csum, 32);
        l_run = l_run * factor + csum;

        // ---- rescale O in C layout: row q = lg*4+r -> factor from lane lg*4+r ----
        float ffac[4];
        #pragma unroll
        for (int r = 0; r < 4; ++r) ffac[r] = __shfl(factor, lg*4 + r);
        #pragma unroll
        for (int dt = 0; dt < 4; ++dt)
            #pragma unroll
            for (int r = 0; r < 4; ++r)
                oacc[dt][r] *= ffac[r];

        // ---- PV: O[q][d] += P[q][key] · V[key][d] ----
        #pragma unroll
        for (int kch = 0; kch < 2; ++kch) {
            s16x8 pa = *(const s16x8*)&Plds[wv][li][kch*32 + lg*8];
            #pragma unroll
            for (int dt = 0; dt < 4; ++dt) {
                s16x8 vb = *(const s16x8*)(Vp + (size_t)(dt*16 + li) * NSEQ + kc + kch*32 + lg*8);
                oacc[dt] = __builtin_amdgcn_mfma_f32_16x16x32_bf16(pa, vb, oacc[dt], 0, 0, 0);
            }
        }
    }

    // ---- epilogue: divide by row sum (output rows are lg*4+r) ----
    float rinv[4];
    #pragma unroll
    for (int r = 0; r < 4; ++r) rinv[r] = 1.0f / __shfl(l_run, lg*4 + r);
    #pragma unroll
    for (int dt = 0; dt < 4; ++dt)
        #pragma unroll
        for (int r = 0; r < 4; ++r)
            O[((size_t)b*NSEQ + qt*64 + wv*16 + lg*4 + r) * DM + h*DKV + dt*16 + li]
                = oacc[dt][r] * rinv[r];
}

// ---------------- residual + LayerNorm ----------------
__global__ __launch_bounds__(256) void ln_kernel(
    const float* __restrict__ Y, const float* __restrict__ gamma,
    const float* __restrict__ beta, float* __restrict__ out)
{
    const int row = blockIdx.x;
    const int t = threadIdx.x;
    const float* y = Y + (size_t)row * DM;
    float4 x = *(const float4*)(y + t*4);
    __shared__ float red[4];
    float s = x.x + x.y + x.z + x.w;
    #pragma unroll
    for (int off = 32; off > 0; off >>= 1) s += __shfl_xor(s, off);
    if ((t & 63) == 0) red[t >> 6] = s;
    __syncthreads();
    float mean = (red[0]+red[1]+red[2]+red[3]) * (1.0f/DM);
    float d0 = x.x-mean, d1 = x.y-mean, d2 = x.z-mean, d3 = x.w-mean;
    float sq = d0*d0 + d1*d1 + d2*d2 + d3*d3;
    __syncthreads();
    #pragma unroll
    for (int off = 32; off > 0; off >>= 1) sq += __shfl_xor(sq, off);
    if ((t & 63) == 0) red[t >> 6] = sq;
    __syncthreads();
    float var = (red[0]+red[1]+red[2]+red[3]) * (1.0f/DM);
    float rstd = rsqrtf(var + LNEPS);
    int c = t * 4;
    float4 g  = *(const float4*)(gamma + c);
    float4 bb = *(const float4*)(beta + c);
    float4 o;
    o.x = d0*rstd*g.x + bb.x;
    o.y = d1*rstd*g.y + bb.y;
    o.z = d2*rstd*g.z + bb.z;
    o.w = d3*rstd*g.w + bb.w;
    *(float4*)(out + (size_t)row*DM + c) = o;
}

extern "C" void kernel_launch(void* const* d_in, const int* in_sizes, int n_in,
                              void* d_out, int out_size, void* d_ws, size_t ws_size,
                              hipStream_t stream)
{
    const float* queries = (const float*)d_in[0];
    const float* keys    = (const float*)d_in[1];
    const float* values  = (const float*)d_in[2];
    const void*  mask    = d_in[3];
    const float* wgt     = (const float*)d_in[4];
    const float* Wq = (const float*)d_in[5];  const float* bq = (const float*)d_in[6];
    const float* Wk = (const float*)d_in[7];  const float* bk = (const float*)d_in[8];
    const float* Wv = (const float*)d_in[9];  const float* bv = (const float*)d_in[10];
    const float* Wo = (const float*)d_in[11]; const float* bo = (const float*)d_in[12];
    const float* gamma = (const float*)d_in[13]; const float* beta = (const float*)d_in[14];
    float* out = (float*)d_out;

    char* ws = (char*)d_ws;
    int* flag = (int*)ws;
    const size_t SZ = (size_t)B_ * H_ * NSEQ * DKV;   // 2M elements per tensor
    short* Qb = (short*)(ws + 256);
    short* Kb = Qb + SZ;
    short* Vt = Kb + SZ;                 // [B][H][64][N] bf16
    float* Ob = (float*)(Vt + SZ);       // attention out, f32 [B][N][H*64]
    float* Yb = Ob + SZ;                 // pre-LN

    detect_mask<<<1, 1, 0, stream>>>((const unsigned*)mask, flag);
    gemm64<<<dim3(16, 32), 256, 0, stream>>>(queries, Wq, bq, nullptr, Qb, 1);
    gemm64<<<dim3(16, 32), 256, 0, stream>>>(keys,    Wk, bk, nullptr, Kb, 1);
    gemm64<<<dim3(16, 32), 256, 0, stream>>>(values,  Wv, bv, nullptr, Vt, 2);
    attn_mfma<<<dim3(16, H_, B_), 256, 0, stream>>>(Qb, Kb, Vt, mask, wgt, flag, Ob);
    gemm64<<<dim3(16, 32), 256, 0, stream>>>(Ob, Wo, bo, queries, Yb, 0);
    ln_kernel<<<dim3(B_*NSEQ), 256, 0, stream>>>(Yb, gamma, beta, out);
}

// Round 4
// 200.807 us; speedup vs baseline: 3.5780x; 1.9146x over previous
//
#include <hip/hip_runtime.h>
#include <hip/hip_bf16.h>
#include <math.h>

#define B_   2
#define H_   16
#define NSEQ 1024
#define DM   1024
#define DKV  64
#define LNEPS 1e-5f

typedef __attribute__((ext_vector_type(8))) short s16x8;
typedef __attribute__((ext_vector_type(4))) float f32x4;
typedef __attribute__((ext_vector_type(4))) unsigned u32x4;

__device__ inline short f2bf(float f) {
    __hip_bfloat16 h = __float2bfloat16(f);
    return *reinterpret_cast<short*>(&h);
}

// ---------------- mask dtype detection ----------------
__global__ void detect_mask(const unsigned* __restrict__ mask_words, int* __restrict__ flag) {
    unsigned f = 0;
    for (int i = 0; i < 256; ++i) f |= (mask_words[i] > 1u) ? 1u : 0u;
    *flag = (int)f;   // 1 => packed uint8 bools, 0 => int32 0/1
}

// ---------------- f32 -> bf16 flat cast ----------------
__global__ __launch_bounds__(256) void cast_bf16(const float* __restrict__ in,
                                                 short* __restrict__ out, int n) {
    int i = (blockIdx.x * 256 + threadIdx.x) * 8;
    if (i >= n) return;
    f32x4 a = *(const f32x4*)(in + i);
    f32x4 b = *(const f32x4*)(in + i + 4);
    s16x8 o;
    o[0]=f2bf(a[0]); o[1]=f2bf(a[1]); o[2]=f2bf(a[2]); o[3]=f2bf(a[3]);
    o[4]=f2bf(b[0]); o[5]=f2bf(b[1]); o[6]=f2bf(b[2]); o[7]=f2bf(b[3]);
    *(s16x8*)(out + i) = o;
}

// ---------------- W[K][N] f32 -> Wt[N][K] bf16 ----------------
__global__ __launch_bounds__(256) void castT_bf16(const float* __restrict__ W,
                                                  short* __restrict__ Wt) {
    __shared__ float tl[32][33];
    const int k0 = blockIdx.y * 32, n0 = blockIdx.x * 32;
    const int r = threadIdx.x >> 3, c4 = (threadIdx.x & 7) * 4;
    *(float4*)&tl[r][c4] = *(const float4*)(W + (size_t)(k0 + r) * DM + n0 + c4);
    __syncthreads();
    unsigned u0 = (unsigned short)f2bf(tl[c4+0][r]) | ((unsigned)(unsigned short)f2bf(tl[c4+1][r]) << 16);
    unsigned u1 = (unsigned short)f2bf(tl[c4+2][r]) | ((unsigned)(unsigned short)f2bf(tl[c4+3][r]) << 16);
    uint2 pk; pk.x = u0; pk.y = u1;
    *(uint2*)(Wt + (size_t)(n0 + r) * DM + k0 + c4) = pk;
}

// ---------------- bf16 MFMA GEMM: C = A @ Wt^T + bias ----------------
// A bf16 [2048][1024] row-major; Wt bf16 [1024][1024] = W^T row-major (k-contig).
// mode 1: bf16 per-head [B][H][N][64]; mode 2: bf16 per-head transposed [B][H][64][N];
// mode 0: f32 row-major + resid.
// 64x64 tile, BK=64, 4 waves 2x2, XOR-swizzled LDS (col ^= (row&7)<<3, 8-short granule).
__global__ __launch_bounds__(256) void gemm_bf16(
    const short* __restrict__ A, const short* __restrict__ Wt,
    const float* __restrict__ bias, const float* __restrict__ resid,
    void* __restrict__ outp, int mode)
{
    const int t  = threadIdx.x;
    const int wv = t >> 6, l = t & 63, lg = l >> 4, li = l & 15;
    const int wr = wv >> 1, wc = wv & 1;
    const int c0 = blockIdx.x * 64, m0 = blockIdx.y * 64;

    __shared__ short Asl[64 * 64];
    __shared__ short Bsl[64 * 64];

    f32x4 acc[2][2] = {};

    const int sr = t >> 2, scol = (t & 3) * 16;      // staging: row, 16-col chunk
    const int sw = (sr & 7) << 3;

    s16x8 a0 = *(const s16x8*)(A  + (size_t)(m0 + sr) * DM + scol);
    s16x8 a1 = *(const s16x8*)(A  + (size_t)(m0 + sr) * DM + scol + 8);
    s16x8 b0 = *(const s16x8*)(Wt + (size_t)(c0 + sr) * DM + scol);
    s16x8 b1 = *(const s16x8*)(Wt + (size_t)(c0 + sr) * DM + scol + 8);

    for (int k0 = 0; k0 < DM; k0 += 64) {
        __syncthreads();   // previous iteration's LDS reads complete
        *(s16x8*)&Asl[sr * 64 + (scol ^ sw)]       = a0;
        *(s16x8*)&Asl[sr * 64 + ((scol + 8) ^ sw)] = a1;
        *(s16x8*)&Bsl[sr * 64 + (scol ^ sw)]       = b0;
        *(s16x8*)&Bsl[sr * 64 + ((scol + 8) ^ sw)] = b1;
        __syncthreads();
        if (k0 + 64 < DM) {   // issue next-tile loads before compute
            a0 = *(const s16x8*)(A  + (size_t)(m0 + sr) * DM + k0 + 64 + scol);
            a1 = *(const s16x8*)(A  + (size_t)(m0 + sr) * DM + k0 + 64 + scol + 8);
            b0 = *(const s16x8*)(Wt + (size_t)(c0 + sr) * DM + k0 + 64 + scol);
            b1 = *(const s16x8*)(Wt + (size_t)(c0 + sr) * DM + k0 + 64 + scol + 8);
        }
        #pragma unroll
        for (int kh = 0; kh < 2; ++kh) {
            s16x8 af[2], bf[2];
            #pragma unroll
            for (int fi = 0; fi < 2; ++fi) {
                const int row = wr * 32 + fi * 16 + li;
                af[fi] = *(const s16x8*)&Asl[row * 64 + ((kh * 32 + lg * 8) ^ ((row & 7) << 3))];
            }
            #pragma unroll
            for (int fj = 0; fj < 2; ++fj) {
                const int row = wc * 32 + fj * 16 + li;
                bf[fj] = *(const s16x8*)&Bsl[row * 64 + ((kh * 32 + lg * 8) ^ ((row & 7) << 3))];
            }
            #pragma unroll
            for (int fi = 0; fi < 2; ++fi)
                #pragma unroll
                for (int fj = 0; fj < 2; ++fj)
                    acc[fi][fj] = __builtin_amdgcn_mfma_f32_16x16x32_bf16(af[fi], bf[fj], acc[fi][fj], 0, 0, 0);
        }
    }

    const int hh = c0 >> 6;   // BN=64 == head width
    #pragma unroll
    for (int fi = 0; fi < 2; ++fi) {
        #pragma unroll
        for (int j = 0; j < 4; ++j) {
            const int m = m0 + wr * 32 + fi * 16 + lg * 4 + j;
            const int bb = m >> 10, n = m & (NSEQ - 1);
            #pragma unroll
            for (int fj = 0; fj < 2; ++fj) {
                const int cc = wc * 32 + fj * 16 + li;     // 0..63 in tile
                const int c  = c0 + cc;
                float v = acc[fi][fj][j] + bias[c];
                if (mode == 1) {
                    ((short*)outp)[(((size_t)(bb * H_ + hh) * NSEQ) + n) * DKV + cc] = f2bf(v);
                } else if (mode == 2) {
                    ((short*)outp)[(((size_t)(bb * H_ + hh) * DKV) + cc) * NSEQ + n] = f2bf(v);
                } else {
                    float* of = (float*)outp;
                    of[(size_t)m * DM + c] = v + resid[(size_t)m * DM + c];
                }
            }
        }
    }
}

// ---------------- flash attention, bf16 MFMA, double-buffered prefetch ----------------
// Swapped QK^T (S^T = K*Q^T); softmax layout q=li, C/O layout q=lg*4+r (shfl between).
// Next chunk's K frags + wgt + mask are register-prefetched while current chunk computes.
// Mask prefetched as bytes unconditionally (in int32 mode those byte reads are in-bounds);
// int32 mode loads uint4 inline instead.

#define LOADC(kc_, kf_, w4_, mb_) do {                                                    \
    _Pragma("unroll") for (int dc = 0; dc < 2; ++dc)                                      \
      _Pragma("unroll") for (int nt = 0; nt < 4; ++nt)                                    \
        kf_[dc*4+nt] = *(const s16x8*)(Kp + (size_t)((kc_) + nt*16 + li) * DKV + dc*32 + lg*8); \
    _Pragma("unroll") for (int nt = 0; nt < 4; ++nt) {                                    \
        w4_[nt] = *(const f32x4*)(wrow + (kc_) + nt*16 + lg*4);                           \
        mb_[nt] = *(const unsigned*)(Mb + moff + (kc_) + nt*16 + lg*4);                   \
    }                                                                                     \
} while (0)

#define PROCESS(kc_, kf_, w4_, mb_) do {                                                  \
    f32x4 sc[4] = {};                                                                     \
    _Pragma("unroll") for (int dc = 0; dc < 2; ++dc)                                      \
      _Pragma("unroll") for (int nt = 0; nt < 4; ++nt)                                    \
        sc[nt] = __builtin_amdgcn_mfma_f32_16x16x32_bf16(kf_[dc*4+nt], qa[dc], sc[nt], 0, 0, 0); \
    s16x8 vf[8];                                                                          \
    _Pragma("unroll") for (int kch = 0; kch < 2; ++kch)                                   \
      _Pragma("unroll") for (int dt = 0; dt < 4; ++dt)                                    \
        vf[kch*4+dt] = *(const s16x8*)(Vp + (size_t)(dt*16 + li) * NSEQ + (kc_) + kch*32 + lg*8); \
    float sv[16]; float cmax = -1e30f;                                                    \
    _Pragma("unroll") for (int nt = 0; nt < 4; ++nt) {                                    \
      unsigned mm[4];                                                                     \
      if (mmode) { unsigned u = mb_[nt];                                                  \
        mm[0] = u & 0xffu; mm[1] = (u >> 8) & 0xffu; mm[2] = (u >> 16) & 0xffu; mm[3] = u >> 24; } \
      else { u32x4 mi = *(const u32x4*)(Mi + moff + (kc_) + nt*16 + lg*4);                \
        mm[0] = mi[0]; mm[1] = mi[1]; mm[2] = mi[2]; mm[3] = mi[3]; }                     \
      _Pragma("unroll") for (int r = 0; r < 4; ++r) {                                     \
        float s = sc[nt][r] * 0.125f * w4_[nt][r];                                        \
        s = mm[r] ? -1e30f : s;                                                           \
        sv[nt*4+r] = s; cmax = fmaxf(cmax, s); } }                                        \
    cmax = fmaxf(cmax, __shfl_xor(cmax, 16));                                             \
    cmax = fmaxf(cmax, __shfl_xor(cmax, 32));                                             \
    const float mnew = fmaxf(m_run, cmax);                                                \
    const float factor = __expf(m_run - mnew);                                            \
    m_run = mnew;                                                                         \
    float csum = 0.f;                                                                     \
    _Pragma("unroll") for (int nt = 0; nt < 4; ++nt) {                                    \
      float p0 = __expf(sv[nt*4+0] - mnew), p1 = __expf(sv[nt*4+1] - mnew);               \
      float p2 = __expf(sv[nt*4+2] - mnew), p3 = __expf(sv[nt*4+3] - mnew);               \
      csum += p0 + p1 + p2 + p3;                                                          \
      unsigned u0 = (unsigned short)f2bf(p0) | ((unsigned)(unsigned short)f2bf(p1) << 16);\
      unsigned u1 = (unsigned short)f2bf(p2) | ((unsigned)(unsigned short)f2bf(p3) << 16);\
      uint2 pk; pk.x = u0; pk.y = u1;                                                     \
      *(uint2*)&Plds[wv][li][nt*16 + lg*4] = pk; }                                        \
    csum += __shfl_xor(csum, 16); csum += __shfl_xor(csum, 32);                           \
    l_run = l_run * factor + csum;                                                        \
    float ffac[4];                                                                        \
    _Pragma("unroll") for (int r = 0; r < 4; ++r) ffac[r] = __shfl(factor, lg*4 + r);     \
    _Pragma("unroll") for (int dt = 0; dt < 4; ++dt)                                      \
      _Pragma("unroll") for (int r = 0; r < 4; ++r) oacc[dt][r] *= ffac[r];               \
    _Pragma("unroll") for (int kch = 0; kch < 2; ++kch) {                                 \
      s16x8 pa = *(const s16x8*)&Plds[wv][li][kch*32 + lg*8];                             \
      _Pragma("unroll") for (int dt = 0; dt < 4; ++dt)                                    \
        oacc[dt] = __builtin_amdgcn_mfma_f32_16x16x32_bf16(pa, vf[kch*4+dt], oacc[dt], 0, 0, 0); } \
} while (0)

__global__ __launch_bounds__(256) void attn_mfma(
    const short* __restrict__ Qb, const short* __restrict__ Kb, const short* __restrict__ Vt,
    const void* __restrict__ mask, const float* __restrict__ wgt,
    const int* __restrict__ flagp, short* __restrict__ O)
{
    const int t  = threadIdx.x;
    const int wv = t >> 6;
    const int l  = t & 63;
    const int lg = l >> 4;
    const int li = l & 15;
    const int qt = blockIdx.x;
    const int h  = blockIdx.y, b = blockIdx.z;
    const size_t bh = (size_t)b * H_ + h;
    const int qrow = qt*64 + wv*16 + li;

    __shared__ short Plds[4][16][80];

    const short* Qp = Qb + (bh * NSEQ + qt*64 + wv*16) * DKV;
    const short* Kp = Kb + bh * NSEQ * DKV;
    const short* Vp = Vt + bh * DKV * NSEQ;
    const float* wrow = wgt + (bh * NSEQ + qrow) * NSEQ;
    const size_t moff = (bh * NSEQ + qrow) * NSEQ;
    const int mmode = *flagp;
    const unsigned* Mi = (const unsigned*)mask;
    const unsigned char* Mb = (const unsigned char*)mask;

    s16x8 qa[2];
    qa[0] = *(const s16x8*)(Qp + (size_t)li * DKV + lg*8);
    qa[1] = *(const s16x8*)(Qp + (size_t)li * DKV + 32 + lg*8);

    float m_run = -1e30f, l_run = 0.f;
    f32x4 oacc[4] = {};

    s16x8 kfa[8], kfb[8];
    f32x4 w4a[4], w4b[4];
    unsigned mba[4], mbb[4];

    LOADC(0, kfa, w4a, mba);
    for (int kc = 0; kc < NSEQ; kc += 128) {
        LOADC(kc + 64, kfb, w4b, mbb);
        PROCESS(kc, kfa, w4a, mba);
        if (kc + 128 < NSEQ) LOADC(kc + 128, kfa, w4a, mba);
        PROCESS(kc + 64, kfb, w4b, mbb);
    }

    float rinv[4];
    #pragma unroll
    for (int r = 0; r < 4; ++r) rinv[r] = 1.0f / __shfl(l_run, lg*4 + r);
    #pragma unroll
    for (int dt = 0; dt < 4; ++dt)
        #pragma unroll
        for (int r = 0; r < 4; ++r)
            O[((size_t)b*NSEQ + qt*64 + wv*16 + lg*4 + r) * DM + h*DKV + dt*16 + li]
                = f2bf(oacc[dt][r] * rinv[r]);
}

// ---------------- residual + LayerNorm ----------------
__global__ __launch_bounds__(256) void ln_kernel(
    const float* __restrict__ Y, const float* __restrict__ gamma,
    const float* __restrict__ beta, float* __restrict__ out)
{
    const int row = blockIdx.x;
    const int t = threadIdx.x;
    const float* y = Y + (size_t)row * DM;
    float4 x = *(const float4*)(y + t*4);
    __shared__ float red[4];
    float s = x.x + x.y + x.z + x.w;
    #pragma unroll
    for (int off = 32; off > 0; off >>= 1) s += __shfl_xor(s, off);
    if ((t & 63) == 0) red[t >> 6] = s;
    __syncthreads();
    float mean = (red[0]+red[1]+red[2]+red[3]) * (1.0f/DM);
    float d0 = x.x-mean, d1 = x.y-mean, d2 = x.z-mean, d3 = x.w-mean;
    float sq = d0*d0 + d1*d1 + d2*d2 + d3*d3;
    __syncthreads();
    #pragma unroll
    for (int off = 32; off > 0; off >>= 1) sq += __shfl_xor(sq, off);
    if ((t & 63) == 0) red[t >> 6] = sq;
    __syncthreads();
    float var = (red[0]+red[1]+red[2]+red[3]) * (1.0f/DM);
    float rstd = rsqrtf(var + LNEPS);
    int c = t * 4;
    float4 g  = *(const float4*)(gamma + c);
    float4 bb = *(const float4*)(beta + c);
    float4 o;
    o.x = d0*rstd*g.x + bb.x;
    o.y = d1*rstd*g.y + bb.y;
    o.z = d2*rstd*g.z + bb.z;
    o.w = d3*rstd*g.w + bb.w;
    *(float4*)(out + (size_t)row*DM + c) = o;
}

extern "C" void kernel_launch(void* const* d_in, const int* in_sizes, int n_in,
                              void* d_out, int out_size, void* d_ws, size_t ws_size,
                              hipStream_t stream)
{
    const float* queries = (const float*)d_in[0];
    const float* keys    = (const float*)d_in[1];
    const float* values  = (const float*)d_in[2];
    const void*  mask    = d_in[3];
    const float* wgt     = (const float*)d_in[4];
    const float* Wq = (const float*)d_in[5];  const float* bq = (const float*)d_in[6];
    const float* Wk = (const float*)d_in[7];  const float* bk = (const float*)d_in[8];
    const float* Wv = (const float*)d_in[9];  const float* bv = (const float*)d_in[10];
    const float* Wo = (const float*)d_in[11]; const float* bo = (const float*)d_in[12];
    const float* gamma = (const float*)d_in[13]; const float* beta = (const float*)d_in[14];
    float* out = (float*)d_out;

    const size_t SZ = (size_t)B_ * NSEQ * DM;      // 2M elements (activations)
    const size_t WSZ = (size_t)DM * DM;            // 1M elements (weights)

    char* ws = (char*)d_ws;
    int* flag  = (int*)ws;
    short* Qa  = (short*)(ws + 256);   // bf16 casts of inputs
    short* Ka  = Qa + SZ;
    short* Va  = Ka + SZ;
    short* Wtq = Va + SZ;              // transposed bf16 weights
    short* Wtk = Wtq + WSZ;
    short* Wtv = Wtk + WSZ;
    short* Wto = Wtv + WSZ;
    short* Qh  = Wto + WSZ;            // per-head Q [B][H][N][64]
    short* Kh  = Qh + SZ;
    short* Vth = Kh + SZ;              // per-head V^T [B][H][64][N]
    short* Ob  = Va;                   // alias: Va dead after V-projection
    float* Yb  = (float*)Qa;           // alias: Qa+Ka dead after projections (8 MB)

    detect_mask<<<1, 1, 0, stream>>>((const unsigned*)mask, flag);
    cast_bf16<<<dim3((int)(SZ/8/256)), 256, 0, stream>>>(queries, Qa, (int)SZ);
    cast_bf16<<<dim3((int)(SZ/8/256)), 256, 0, stream>>>(keys,    Ka, (int)SZ);
    cast_bf16<<<dim3((int)(SZ/8/256)), 256, 0, stream>>>(values,  Va, (int)SZ);
    castT_bf16<<<dim3(32, 32), 256, 0, stream>>>(Wq, Wtq);
    castT_bf16<<<dim3(32, 32), 256, 0, stream>>>(Wk, Wtk);
    castT_bf16<<<dim3(32, 32), 256, 0, stream>>>(Wv, Wtv);
    castT_bf16<<<dim3(32, 32), 256, 0, stream>>>(Wo, Wto);

    gemm_bf16<<<dim3(16, 32), 256, 0, stream>>>(Qa, Wtq, bq, nullptr, Qh, 1);
    gemm_bf16<<<dim3(16, 32), 256, 0, stream>>>(Ka, Wtk, bk, nullptr, Kh, 1);
    gemm_bf16<<<dim3(16, 32), 256, 0, stream>>>(Va, Wtv, bv, nullptr, Vth, 2);

    attn_mfma<<<dim3(16, H_, B_), 256, 0, stream>>>(Qh, Kh, Vth, mask, wgt, flag, Ob);

    gemm_bf16<<<dim3(16, 32), 256, 0, stream>>>(Ob, Wto, bo, queries, Yb, 0);
    ln_kernel<<<dim3(B_*NSEQ), 256, 0, stream>>>(Yb, gamma, beta, out);
}

// Round 5
// 193.576 us; speedup vs baseline: 3.7117x; 1.0374x over previous
//
#include <hip/hip_runtime.h>
#include <hip/hip_bf16.h>
#include <math.h>

#define B_   2
#define H_   16
#define NSEQ 1024
#define DM   1024
#define DKV  64
#define NSPLIT 4
#define KPB  (NSEQ / NSPLIT)   // 256 keys per block
#define LNEPS 1e-5f

typedef __attribute__((ext_vector_type(8))) short s16x8;
typedef __attribute__((ext_vector_type(4))) float f32x4;
typedef __attribute__((ext_vector_type(4))) unsigned u32x4;

__device__ inline short f2bf(float f) {
    __hip_bfloat16 h = __float2bfloat16(f);
    return *reinterpret_cast<short*>(&h);
}
__device__ inline float bf2f(short s) {
    unsigned u = ((unsigned)(unsigned short)s) << 16;
    return __uint_as_float(u);
}

// ---------------- mask dtype detection ----------------
__global__ void detect_mask(const unsigned* __restrict__ mask_words, int* __restrict__ flag) {
    unsigned f = 0;
    for (int i = 0; i < 256; ++i) f |= (mask_words[i] > 1u) ? 1u : 0u;
    *flag = (int)f;   // 1 => packed uint8 bools, 0 => int32 0/1
}

// ---------------- f32 -> bf16 flat cast (q,k,v in one launch) ----------------
__global__ __launch_bounds__(256) void cast3_bf16(
    const float* __restrict__ q, const float* __restrict__ k, const float* __restrict__ v,
    short* __restrict__ qo, short* __restrict__ ko, short* __restrict__ vo, int n) {
    const float* in = blockIdx.y == 0 ? q : (blockIdx.y == 1 ? k : v);
    short* out      = blockIdx.y == 0 ? qo : (blockIdx.y == 1 ? ko : vo);
    int i = (blockIdx.x * 256 + threadIdx.x) * 8;
    if (i >= n) return;
    f32x4 a = *(const f32x4*)(in + i);
    f32x4 b = *(const f32x4*)(in + i + 4);
    s16x8 o;
    o[0]=f2bf(a[0]); o[1]=f2bf(a[1]); o[2]=f2bf(a[2]); o[3]=f2bf(a[3]);
    o[4]=f2bf(b[0]); o[5]=f2bf(b[1]); o[6]=f2bf(b[2]); o[7]=f2bf(b[3]);
    *(s16x8*)(out + i) = o;
}

// ---------------- W[K][N] f32 -> Wt[N][K] bf16 (4 weights in one launch) ----------------
__global__ __launch_bounds__(256) void castT4_bf16(
    const float* __restrict__ w0, const float* __restrict__ w1,
    const float* __restrict__ w2, const float* __restrict__ w3,
    short* __restrict__ t0, short* __restrict__ t1,
    short* __restrict__ t2, short* __restrict__ t3) {
    const float* W = blockIdx.z == 0 ? w0 : (blockIdx.z == 1 ? w1 : (blockIdx.z == 2 ? w2 : w3));
    short* Wt      = blockIdx.z == 0 ? t0 : (blockIdx.z == 1 ? t1 : (blockIdx.z == 2 ? t2 : t3));
    __shared__ float tl[32][33];
    const int k0 = blockIdx.y * 32, n0 = blockIdx.x * 32;
    const int r = threadIdx.x >> 3, c4 = (threadIdx.x & 7) * 4;
    *(float4*)&tl[r][c4] = *(const float4*)(W + (size_t)(k0 + r) * DM + n0 + c4);
    __syncthreads();
    unsigned u0 = (unsigned short)f2bf(tl[c4+0][r]) | ((unsigned)(unsigned short)f2bf(tl[c4+1][r]) << 16);
    unsigned u1 = (unsigned short)f2bf(tl[c4+2][r]) | ((unsigned)(unsigned short)f2bf(tl[c4+3][r]) << 16);
    uint2 pk; pk.x = u0; pk.y = u1;
    *(uint2*)(Wt + (size_t)(n0 + r) * DM + k0 + c4) = pk;
}

// ---------------- bf16 MFMA GEMM: C = A @ Wt^T + bias ----------------
__global__ __launch_bounds__(256) void gemm_bf16(
    const short* __restrict__ A, const short* __restrict__ Wt,
    const float* __restrict__ bias, const float* __restrict__ resid,
    void* __restrict__ outp, int mode)
{
    const int t  = threadIdx.x;
    const int wv = t >> 6, l = t & 63, lg = l >> 4, li = l & 15;
    const int wr = wv >> 1, wc = wv & 1;
    const int c0 = blockIdx.x * 64, m0 = blockIdx.y * 64;

    __shared__ short Asl[64 * 64];
    __shared__ short Bsl[64 * 64];

    f32x4 acc[2][2] = {};

    const int sr = t >> 2, scol = (t & 3) * 16;
    const int sw = (sr & 7) << 3;

    s16x8 a0 = *(const s16x8*)(A  + (size_t)(m0 + sr) * DM + scol);
    s16x8 a1 = *(const s16x8*)(A  + (size_t)(m0 + sr) * DM + scol + 8);
    s16x8 b0 = *(const s16x8*)(Wt + (size_t)(c0 + sr) * DM + scol);
    s16x8 b1 = *(const s16x8*)(Wt + (size_t)(c0 + sr) * DM + scol + 8);

    for (int k0 = 0; k0 < DM; k0 += 64) {
        __syncthreads();
        *(s16x8*)&Asl[sr * 64 + (scol ^ sw)]       = a0;
        *(s16x8*)&Asl[sr * 64 + ((scol + 8) ^ sw)] = a1;
        *(s16x8*)&Bsl[sr * 64 + (scol ^ sw)]       = b0;
        *(s16x8*)&Bsl[sr * 64 + ((scol + 8) ^ sw)] = b1;
        __syncthreads();
        if (k0 + 64 < DM) {
            a0 = *(const s16x8*)(A  + (size_t)(m0 + sr) * DM + k0 + 64 + scol);
            a1 = *(const s16x8*)(A  + (size_t)(m0 + sr) * DM + k0 + 64 + scol + 8);
            b0 = *(const s16x8*)(Wt + (size_t)(c0 + sr) * DM + k0 + 64 + scol);
            b1 = *(const s16x8*)(Wt + (size_t)(c0 + sr) * DM + k0 + 64 + scol + 8);
        }
        #pragma unroll
        for (int kh = 0; kh < 2; ++kh) {
            s16x8 af[2], bf[2];
            #pragma unroll
            for (int fi = 0; fi < 2; ++fi) {
                const int row = wr * 32 + fi * 16 + li;
                af[fi] = *(const s16x8*)&Asl[row * 64 + ((kh * 32 + lg * 8) ^ ((row & 7) << 3))];
            }
            #pragma unroll
            for (int fj = 0; fj < 2; ++fj) {
                const int row = wc * 32 + fj * 16 + li;
                bf[fj] = *(const s16x8*)&Bsl[row * 64 + ((kh * 32 + lg * 8) ^ ((row & 7) << 3))];
            }
            #pragma unroll
            for (int fi = 0; fi < 2; ++fi)
                #pragma unroll
                for (int fj = 0; fj < 2; ++fj)
                    acc[fi][fj] = __builtin_amdgcn_mfma_f32_16x16x32_bf16(af[fi], bf[fj], acc[fi][fj], 0, 0, 0);
        }
    }

    const int hh = c0 >> 6;
    #pragma unroll
    for (int fi = 0; fi < 2; ++fi) {
        #pragma unroll
        for (int j = 0; j < 4; ++j) {
            const int m = m0 + wr * 32 + fi * 16 + lg * 4 + j;
            const int bb = m >> 10, n = m & (NSEQ - 1);
            #pragma unroll
            for (int fj = 0; fj < 2; ++fj) {
                const int cc = wc * 32 + fj * 16 + li;
                const int c  = c0 + cc;
                float v = acc[fi][fj][j] + bias[c];
                if (mode == 1) {
                    ((short*)outp)[(((size_t)(bb * H_ + hh) * NSEQ) + n) * DKV + cc] = f2bf(v);
                } else if (mode == 2) {
                    ((short*)outp)[(((size_t)(bb * H_ + hh) * DKV) + cc) * NSEQ + n] = f2bf(v);
                } else {
                    float* of = (float*)outp;
                    of[(size_t)m * DM + c] = v + resid[(size_t)m * DM + c];
                }
            }
        }
    }
}

// ---------------- flash attention, split-K (flash-decode) ----------------
// blockIdx.x = qt*NSPLIT + s : each block does 64 q-rows x 256 keys.
// Swapped QK^T; softmax layout q=li, C/O layout q=lg*4+r. Partials (m, l,
// unnormalized bf16 O) go to ws; combine kernel merges splits + normalizes.
__global__ __launch_bounds__(256) void attn_split(
    const short* __restrict__ Qb, const short* __restrict__ Kb, const short* __restrict__ Vt,
    const void* __restrict__ mask, const float* __restrict__ wgt,
    const int* __restrict__ flagp, short* __restrict__ Opart,
    float* __restrict__ mpart, float* __restrict__ lpart)
{
    const int t  = threadIdx.x;
    const int wv = t >> 6;
    const int l  = t & 63;
    const int lg = l >> 4;
    const int li = l & 15;
    const int qt = blockIdx.x >> 2;          // 0..15
    const int sp = blockIdx.x & (NSPLIT-1);  // 0..3
    const int h  = blockIdx.y, b = blockIdx.z;
    const size_t bh = (size_t)b * H_ + h;
    const int qrow = qt*64 + wv*16 + li;     // softmax-layout row
    const int kbase = sp * KPB;

    __shared__ short Plds[4][16][80];

    const short* Qp = Qb + (bh * NSEQ + qt*64 + wv*16) * DKV;
    const short* Kp = Kb + bh * NSEQ * DKV;
    const short* Vp = Vt + bh * DKV * NSEQ;
    const float* wrow = wgt + (bh * NSEQ + qrow) * NSEQ;
    const size_t moff = (bh * NSEQ + qrow) * NSEQ;
    const int mmode = *flagp;
    const unsigned* Mi = (const unsigned*)mask;
    const unsigned char* Mb = (const unsigned char*)mask;

    s16x8 qa[2];
    qa[0] = *(const s16x8*)(Qp + (size_t)li * DKV + lg*8);
    qa[1] = *(const s16x8*)(Qp + (size_t)li * DKV + 32 + lg*8);

    float m_run = -1e30f, l_run = 0.f;
    f32x4 oacc[4] = {};

    for (int kc = kbase; kc < kbase + KPB; kc += 64) {
        // S^T = K * Q^T : sc[nt][r] = S[q=li][key=kc+nt*16+lg*4+r]
        f32x4 sc[4] = {};
        #pragma unroll
        for (int dc = 0; dc < 2; ++dc)
            #pragma unroll
            for (int nt = 0; nt < 4; ++nt) {
                s16x8 kb = *(const s16x8*)(Kp + (size_t)(kc + nt*16 + li) * DKV + dc*32 + lg*8);
                sc[nt] = __builtin_amdgcn_mfma_f32_16x16x32_bf16(kb, qa[dc], sc[nt], 0, 0, 0);
            }

        // hoist V fragment loads (used after softmax)
        s16x8 vf[8];
        #pragma unroll
        for (int kch = 0; kch < 2; ++kch)
            #pragma unroll
            for (int dt = 0; dt < 4; ++dt)
                vf[kch*4+dt] = *(const s16x8*)(Vp + (size_t)(dt*16 + li) * NSEQ + kc + kch*32 + lg*8);

        // scale * weights, mask, online softmax (softmax layout)
        float sv[16];
        float cmax = -1e30f;
        #pragma unroll
        for (int nt = 0; nt < 4; ++nt) {
            const int k4 = kc + nt*16 + lg*4;
            f32x4 w4 = *(const f32x4*)(wrow + k4);
            unsigned mm[4];
            if (mmode) {
                unsigned u = *(const unsigned*)(Mb + moff + k4);
                mm[0] = u & 0xffu; mm[1] = (u >> 8) & 0xffu;
                mm[2] = (u >> 16) & 0xffu; mm[3] = u >> 24;
            } else {
                u32x4 mi = *(const u32x4*)(Mi + moff + k4);
                mm[0] = mi[0]; mm[1] = mi[1]; mm[2] = mi[2]; mm[3] = mi[3];
            }
            #pragma unroll
            for (int r = 0; r < 4; ++r) {
                float s = sc[nt][r] * 0.125f * w4[r];
                s = mm[r] ? -1e30f : s;
                sv[nt*4 + r] = s;
                cmax = fmaxf(cmax, s);
            }
        }
        cmax = fmaxf(cmax, __shfl_xor(cmax, 16));
        cmax = fmaxf(cmax, __shfl_xor(cmax, 32));
        const float mnew = fmaxf(m_run, cmax);
        const float factor = __expf(m_run - mnew);
        m_run = mnew;

        float csum = 0.f;
        #pragma unroll
        for (int nt = 0; nt < 4; ++nt) {
            float p0 = __expf(sv[nt*4+0] - mnew), p1 = __expf(sv[nt*4+1] - mnew);
            float p2 = __expf(sv[nt*4+2] - mnew), p3 = __expf(sv[nt*4+3] - mnew);
            csum += p0 + p1 + p2 + p3;
            unsigned u0 = (unsigned short)f2bf(p0) | ((unsigned)(unsigned short)f2bf(p1) << 16);
            unsigned u1 = (unsigned short)f2bf(p2) | ((unsigned)(unsigned short)f2bf(p3) << 16);
            uint2 pk; pk.x = u0; pk.y = u1;
            *(uint2*)&Plds[wv][li][nt*16 + lg*4] = pk;
        }
        csum += __shfl_xor(csum, 16);
        csum += __shfl_xor(csum, 32);
        l_run = l_run * factor + csum;

        // rescale O in C layout (factor from lane lg*4+r)
        float ffac[4];
        #pragma unroll
        for (int r = 0; r < 4; ++r) ffac[r] = __shfl(factor, lg*4 + r);
        #pragma unroll
        for (int dt = 0; dt < 4; ++dt)
            #pragma unroll
            for (int r = 0; r < 4; ++r)
                oacc[dt][r] *= ffac[r];

        // PV
        #pragma unroll
        for (int kch = 0; kch < 2; ++kch) {
            s16x8 pa = *(const s16x8*)&Plds[wv][li][kch*32 + lg*8];
            #pragma unroll
            for (int dt = 0; dt < 4; ++dt)
                oacc[dt] = __builtin_amdgcn_mfma_f32_16x16x32_bf16(pa, vf[kch*4+dt], oacc[dt], 0, 0, 0);
        }
    }

    // ---- write partials ----
    const size_t SBH = (size_t)B_ * H_ * NSEQ;
    if (lg == 0) {
        mpart[(size_t)sp * SBH + bh * NSEQ + qrow] = m_run;
        lpart[(size_t)sp * SBH + bh * NSEQ + qrow] = l_run;
    }
    #pragma unroll
    for (int dt = 0; dt < 4; ++dt)
        #pragma unroll
        for (int r = 0; r < 4; ++r)
            Opart[((size_t)sp * SBH + bh * NSEQ + qt*64 + wv*16 + lg*4 + r) * DKV + dt*16 + li]
                = f2bf(oacc[dt][r]);
}

// ---------------- split combine: merge m/l/O partials, normalize, write bf16 Ob ----------------
__global__ __launch_bounds__(256) void attn_combine(
    const short* __restrict__ Opart, const float* __restrict__ mpart,
    const float* __restrict__ lpart, short* __restrict__ Ob)
{
    const size_t SBH = (size_t)B_ * H_ * NSEQ;
    const int R = blockIdx.x * 4 + (threadIdx.x >> 6);   // row in [0, B*H*N)
    const int d = threadIdx.x & 63;
    const int bh = R >> 10, n = R & (NSEQ - 1);
    const int b = bh >> 4, h = bh & (H_ - 1);

    float ms[NSPLIT];
    float mstar = -1e30f;
    #pragma unroll
    for (int s = 0; s < NSPLIT; ++s) {
        ms[s] = mpart[(size_t)s * SBH + R];
        mstar = fmaxf(mstar, ms[s]);
    }
    float lstar = 0.f, acc = 0.f;
    #pragma unroll
    for (int s = 0; s < NSPLIT; ++s) {
        float w = __expf(ms[s] - mstar);
        lstar += w * lpart[(size_t)s * SBH + R];
        acc   += w * bf2f(Opart[((size_t)s * SBH + R) * DKV + d]);
    }
    Ob[((size_t)b * NSEQ + n) * DM + h * DKV + d] = f2bf(acc / lstar);
}

// ---------------- residual + LayerNorm ----------------
__global__ __launch_bounds__(256) void ln_kernel(
    const float* __restrict__ Y, const float* __restrict__ gamma,
    const float* __restrict__ beta, float* __restrict__ out)
{
    const int row = blockIdx.x;
    const int t = threadIdx.x;
    const float* y = Y + (size_t)row * DM;
    float4 x = *(const float4*)(y + t*4);
    __shared__ float red[4];
    float s = x.x + x.y + x.z + x.w;
    #pragma unroll
    for (int off = 32; off > 0; off >>= 1) s += __shfl_xor(s, off);
    if ((t & 63) == 0) red[t >> 6] = s;
    __syncthreads();
    float mean = (red[0]+red[1]+red[2]+red[3]) * (1.0f/DM);
    float d0 = x.x-mean, d1 = x.y-mean, d2 = x.z-mean, d3 = x.w-mean;
    float sq = d0*d0 + d1*d1 + d2*d2 + d3*d3;
    __syncthreads();
    #pragma unroll
    for (int off = 32; off > 0; off >>= 1) sq += __shfl_xor(sq, off);
    if ((t & 63) == 0) red[t >> 6] = sq;
    __syncthreads();
    float var = (red[0]+red[1]+red[2]+red[3]) * (1.0f/DM);
    float rstd = rsqrtf(var + LNEPS);
    int c = t * 4;
    float4 g  = *(const float4*)(gamma + c);
    float4 bb = *(const float4*)(beta + c);
    float4 o;
    o.x = d0*rstd*g.x + bb.x;
    o.y = d1*rstd*g.y + bb.y;
    o.z = d2*rstd*g.z + bb.z;
    o.w = d3*rstd*g.w + bb.w;
    *(float4*)(out + (size_t)row*DM + c) = o;
}

extern "C" void kernel_launch(void* const* d_in, const int* in_sizes, int n_in,
                              void* d_out, int out_size, void* d_ws, size_t ws_size,
                              hipStream_t stream)
{
    const float* queries = (const float*)d_in[0];
    const float* keys    = (const float*)d_in[1];
    const float* values  = (const float*)d_in[2];
    const void*  mask    = d_in[3];
    const float* wgt     = (const float*)d_in[4];
    const float* Wq = (const float*)d_in[5];  const float* bq = (const float*)d_in[6];
    const float* Wk = (const float*)d_in[7];  const float* bk = (const float*)d_in[8];
    const float* Wv = (const float*)d_in[9];  const float* bv = (const float*)d_in[10];
    const float* Wo = (const float*)d_in[11]; const float* bo = (const float*)d_in[12];
    const float* gamma = (const float*)d_in[13]; const float* beta = (const float*)d_in[14];
    float* out = (float*)d_out;

    const size_t SZ  = (size_t)B_ * NSEQ * DM;     // 2M elements
    const size_t WSZ = (size_t)DM * DM;            // 1M elements
    const size_t SBH = (size_t)B_ * H_ * NSEQ;     // 32K rows

    char* ws = (char*)d_ws;
    int* flag  = (int*)ws;
    short* Qa  = (short*)(ws + 256);
    short* Ka  = Qa + SZ;
    short* Va  = Ka + SZ;
    short* Wtq = Va + SZ;
    short* Wtk = Wtq + WSZ;
    short* Wtv = Wtk + WSZ;
    short* Wto = Wtv + WSZ;
    short* Qh  = Wto + WSZ;
    short* Kh  = Qh + SZ;
    short* Vth = Kh + SZ;
    short* Opart = Vth + SZ;                 // [S][B*H*N][64] bf16, 16 MB
    float* mpart = (float*)(Opart + (size_t)NSPLIT * SBH * DKV);
    float* lpart = mpart + (size_t)NSPLIT * SBH;
    short* Ob  = Va;                         // alias: Va dead after V-projection
    float* Yb  = (float*)Qa;                 // alias: Qa+Ka dead after projections

    detect_mask<<<1, 1, 0, stream>>>((const unsigned*)mask, flag);
    cast3_bf16<<<dim3((int)(SZ/8/256), 3), 256, 0, stream>>>(queries, keys, values, Qa, Ka, Va, (int)SZ);
    castT4_bf16<<<dim3(32, 32, 4), 256, 0, stream>>>(Wq, Wk, Wv, Wo, Wtq, Wtk, Wtv, Wto);

    gemm_bf16<<<dim3(16, 32), 256, 0, stream>>>(Qa, Wtq, bq, nullptr, Qh, 1);
    gemm_bf16<<<dim3(16, 32), 256, 0, stream>>>(Ka, Wtk, bk, nullptr, Kh, 1);
    gemm_bf16<<<dim3(16, 32), 256, 0, stream>>>(Va, Wtv, bv, nullptr, Vth, 2);

    attn_split<<<dim3(16 * NSPLIT, H_, B_), 256, 0, stream>>>(Qh, Kh, Vth, mask, wgt, flag,
                                                              Opart, mpart, lpart);
    attn_combine<<<dim3((int)(SBH / 4)), 256, 0, stream>>>(Opart, mpart, lpart, Ob);

    gemm_bf16<<<dim3(16, 32), 256, 0, stream>>>(Ob, Wto, bo, queries, Yb, 0);
    ln_kernel<<<dim3(B_*NSEQ), 256, 0, stream>>>(Yb, gamma, beta, out);
}